// Round 5
// baseline (217.550 us; speedup 1.0000x reference)
//
#include <hip/hip_runtime.h>

// KDE joint histogram = dense split-K bf16 MFMA GEMM, single kernel with a
// MANUAL device-scope grid barrier (cooperative launch was rejected by the
// runtime's occupancy validation; all 496 blocks are provably co-resident:
// 50.2 KB LDS -> >=2 blocks/CU -> >=512 capacity >= 496, so spin is safe).
// Phase 1: per-(tile,chunk,batch) block computes on-the-fly bf16 kx/ky tiles
//          in LDS (exp2 + v_perm bf16 pair-pack), MFMA-accumulates 128x128
//          f32, stores split-K partials to d_ws, atomicAdds tile-sum to norm.
// Barrier: release ticket++; 256 reducer blocks acquire-spin to 496.
// Phase 2: reducers sum 31 partials/cell in regs, scale by 1/norm, store out.

#define B_     4
#define N_     50000
#define M_     256
#define BM     128
#define BN     128
#define BK     64
#define NCH    31               // split-K chunks: grid 4*31*4 = 496 blocks
#define NBLK   496
#define KSTEPS 26               // 26*64 = 1664/chunk; 31*1664 = 51584 >= N
#define KCH    (KSTEPS * BK)
#define LDK    72               // row stride in shorts (144 B, 16B-aligned)
#define BLOCK  256
#define CSCALE 0.84932180f      // sqrt(0.5*log2(e)): exp(-0.5 d^2)=2^(-(d*C)^2)

#if __has_builtin(__builtin_amdgcn_exp2f)
  #define EXPN(t2) __builtin_amdgcn_exp2f(-(t2))
#else
  #define EXPN(t2) __expf(-(t2) * 0.69314718f)
#endif

typedef __attribute__((ext_vector_type(8))) short bf16x8;
typedef __attribute__((ext_vector_type(4))) float f32x4;

// round-half-up bf16 pair pack: low16 = bf16(a), high16 = bf16(b)
__device__ __forceinline__ unsigned pack2bf(float a, float b) {
    unsigned ua = __builtin_bit_cast(unsigned, a) + 0x8000u;
    unsigned ub = __builtin_bit_cast(unsigned, b) + 0x8000u;
    return __builtin_amdgcn_perm(ub, ua, 0x07060302u);  // [ua2,ua3,ub2,ub3]
}

__global__ __launch_bounds__(BLOCK) void kde_all(
    const float* __restrict__ xs, const float* __restrict__ ys,
    const float* __restrict__ bins, float* __restrict__ partial,
    float* __restrict__ ws2, float* __restrict__ out)
{
    __shared__ short As[BM][LDK];     // 18432 B  kx tile [i-bin][k]
    __shared__ short Bs[BN][LDK];     // 18432 B  ky tile [j-bin][k]
    __shared__ float px[KCH];         // 6656 B
    __shared__ float py[KCH];         // 6656 B
    __shared__ float sred[4];

    const int tid   = threadIdx.x;
    const int tile  = blockIdx.x;            // 0..3 -> 2x2 tiles of 128
    const int chunk = blockIdx.y;            // 0..NCH-1
    const int b     = blockIdx.z;

    const int ilo = (tile & 1) * BM;
    const int jlo = (tile >> 1) * BN;
    const float s = CSCALE / (bins[1] - bins[0]);

    // ---- stage this chunk's particles (scaled) into LDS ----
    const float* xb = xs + b * N_;
    const float* yb = ys + b * N_;
    const int k0 = chunk * KCH;
    for (int t = tid; t < KCH; t += BLOCK) {
        const int k = k0 + t;
        const bool ok = (k < N_);
        px[t] = ok ? xb[k] * s : 3.0e30f;    // pad -> t^2 = inf -> exp2(-inf)=0
        py[t] = ok ? yb[k] * s : 3.0e30f;
    }

    // staging role: thread covers bin=tid>>1, k-half kh
    const int  sbin = tid >> 1;
    const int  kh   = (tid & 1) * 32;
    const float bxs = bins[ilo + sbin] * s;
    const float bys = bins[jlo + sbin] * s;

    // MFMA role: 4 waves in 2x2, each owns 64x64 of the 128x128 tile
    const int w    = tid >> 6;
    const int wi   = (w >> 1) * 64;
    const int wj   = (w & 1) * 64;
    const int lane = tid & 63;
    const int lm   = lane & 15;
    const int quad = lane >> 4;

    f32x4 zero = {0.f, 0.f, 0.f, 0.f};
    f32x4 acc[4][4];
    #pragma unroll
    for (int mt = 0; mt < 4; ++mt)
        #pragma unroll
        for (int nt = 0; nt < 4; ++nt) acc[mt][nt] = zero;

    for (int ks = 0; ks < KSTEPS; ++ks) {
        const int kb = ks * BK;
        __syncthreads();                      // covers px/py staging on ks==0
        // ---- 32 kx + 32 ky bf16 elements into LDS ----
        #pragma unroll
        for (int g = 0; g < 4; ++g) {
            const int k8 = kb + kh + g * 8;
            const float4 xa = *(const float4*)&px[k8];
            const float4 xc = *(const float4*)&px[k8 + 4];
            const float4 ya = *(const float4*)&py[k8];
            const float4 yc = *(const float4*)&py[k8 + 4];
            uint4 av, bv;
            float t0, t1;
            t0 = xa.x - bxs; t1 = xa.y - bxs; av.x = pack2bf(EXPN(t0*t0), EXPN(t1*t1));
            t0 = xa.z - bxs; t1 = xa.w - bxs; av.y = pack2bf(EXPN(t0*t0), EXPN(t1*t1));
            t0 = xc.x - bxs; t1 = xc.y - bxs; av.z = pack2bf(EXPN(t0*t0), EXPN(t1*t1));
            t0 = xc.z - bxs; t1 = xc.w - bxs; av.w = pack2bf(EXPN(t0*t0), EXPN(t1*t1));
            t0 = ya.x - bys; t1 = ya.y - bys; bv.x = pack2bf(EXPN(t0*t0), EXPN(t1*t1));
            t0 = ya.z - bys; t1 = ya.w - bys; bv.y = pack2bf(EXPN(t0*t0), EXPN(t1*t1));
            t0 = yc.x - bys; t1 = yc.y - bys; bv.z = pack2bf(EXPN(t0*t0), EXPN(t1*t1));
            t0 = yc.z - bys; t1 = yc.w - bys; bv.w = pack2bf(EXPN(t0*t0), EXPN(t1*t1));
            *(uint4*)&As[sbin][kh + g * 8] = av;
            *(uint4*)&Bs[sbin][kh + g * 8] = bv;
        }
        __syncthreads();
        // ---- consume: 2 K-steps of 32, 16 MFMAs each ----
        #pragma unroll
        for (int kk = 0; kk < BK; kk += 32) {
            bf16x8 af[4], bfr[4];
            #pragma unroll
            for (int t4 = 0; t4 < 4; ++t4)
                af[t4] = *(const bf16x8*)&As[wi + t4 * 16 + lm][kk + quad * 8];
            #pragma unroll
            for (int t4 = 0; t4 < 4; ++t4)
                bfr[t4] = *(const bf16x8*)&Bs[wj + t4 * 16 + lm][kk + quad * 8];
            #pragma unroll
            for (int mt = 0; mt < 4; ++mt)
                #pragma unroll
                for (int nt = 0; nt < 4; ++nt)
                    acc[mt][nt] = __builtin_amdgcn_mfma_f32_16x16x32_bf16(
                        af[mt], bfr[nt], acc[mt][nt], 0, 0, 0);
        }
    }

    // ---- store split-K partial (C/D layout: col=lane&15, row=quad*4+reg) ----
    float tsum = 0.f;
    {
        float* pb = partial + (((size_t)chunk * B_ + b) << 16);
        #pragma unroll
        for (int mt = 0; mt < 4; ++mt) {
            const int row0 = ilo + wi + mt * 16 + quad * 4;
            #pragma unroll
            for (int nt = 0; nt < 4; ++nt) {
                const int col = jlo + wj + nt * 16 + lm;
                const f32x4 a = acc[mt][nt];
                #pragma unroll
                for (int e = 0; e < 4; ++e) {
                    pb[(size_t)(row0 + e) * M_ + col] = a[e];
                    tsum += a[e];
                }
            }
        }
    }

    // ---- norm partial + barrier arrive ----
    #pragma unroll
    for (int off = 32; off; off >>= 1) tsum += __shfl_xor(tsum, off);
    if (lane == 0) sred[w] = tsum;
    __syncthreads();                      // all partial stores + sred done
    unsigned* cnt = (unsigned*)(ws2 + 4);
    if (tid == 0) {
        atomicAdd(&ws2[b], sred[0] + sred[1] + sred[2] + sred[3]);
        __threadfence();                  // agent-scope release of stores
        __hip_atomic_fetch_add(cnt, 1u, __ATOMIC_RELEASE, __HIP_MEMORY_SCOPE_AGENT);
    }

    const int bid = (blockIdx.z * gridDim.y + blockIdx.y) * gridDim.x + blockIdx.x;
    if (bid >= 256) return;               // 240 blocks done; frees CUs

    // ---- barrier wait (cannot deadlock: all 496 blocks co-resident) ----
    if (tid == 0) {
        while (__hip_atomic_load(cnt, __ATOMIC_ACQUIRE, __HIP_MEMORY_SCOPE_AGENT) < (unsigned)NBLK)
            __builtin_amdgcn_s_sleep(2);
    }
    __syncthreads();
    __threadfence();                      // acquire-side fence for all threads

    // ---- phase 2: reduce 31 partials per cell in regs, scale, store ----
    const int cellIdx = bid * 256 + tid;  // float4 index, 16384 per batch
    const int bb = cellIdx >> 14;
    const int cb = cellIdx & 16383;
    const float4* p4 = (const float4*)partial;
    float4 vsum = {0.f, 0.f, 0.f, 0.f};
    #pragma unroll 4
    for (int c = 0; c < NCH; ++c) {
        const float4 v = p4[(((size_t)c * B_ + bb) << 14) + cb];
        vsum.x += v.x; vsum.y += v.y; vsum.z += v.z; vsum.w += v.w;
    }
    const float nrm = __hip_atomic_load(&ws2[bb], __ATOMIC_RELAXED, __HIP_MEMORY_SCOPE_AGENT);
    const float sc = 1.0f / (nrm + 1e-10f);
    vsum.x *= sc; vsum.y *= sc; vsum.z *= sc; vsum.w *= sc;
    ((float4*)out)[cellIdx] = vsum;
}

extern "C" void kernel_launch(void* const* d_in, const int* in_sizes, int n_in,
                              void* d_out, int out_size, void* d_ws, size_t ws_size,
                              hipStream_t stream)
{
    const float* xs   = (const float*)d_in[0];
    const float* ys   = (const float*)d_in[1];
    const float* bins = (const float*)d_in[2];
    float* out     = (float*)d_out;
    float* partial = (float*)d_ws;                          // 31 MB
    float* ws2     = partial + (size_t)NCH * B_ * M_ * M_;  // norm[4] + counter

    hipMemsetAsync(ws2, 0, 32, stream);
    kde_all<<<dim3(4, NCH, B_), dim3(BLOCK), 0, stream>>>(xs, ys, bins, partial, ws2, out);
}

// Round 6
// 152.389 us; speedup vs baseline: 1.4276x; 1.4276x over previous
//
#include <hip/hip_runtime.h>

// KDE joint histogram = dense split-K bf16 MFMA GEMM, atomic-accumulate version.
// joint[b,i,j] = sum_k kx[b,k,i]*ky[b,k,j], kx = exp(-0.5*((x-bin_i)/bw)^2).
// Per-(tile,chunk,batch) block computes on-the-fly bf16 kx/ky tiles in LDS
// (packed f32x2 math + exp2 + packed bf16 convert), MFMA-accumulates 128x128
// f32 in regs, then unsafeAtomicAdd's into a 1 MB f32 accumulator in d_ws
// (no split-K partial arrays, no grid barrier). Block sums -> ws2 by plain
// store. Tail kernel: per-batch norm from ws2 + scale + store to d_out.

#define B_     4
#define N_     50000
#define M_     256
#define BM     128
#define BN     128
#define BK     64
#define NCH    64               // split-K chunks: grid 4*64*4 = 1024 blocks
#define KSTEPS 13               // 13*64 = 832/chunk; 64*832 = 53248 >= N
#define KCH    (KSTEPS * BK)
#define LDK    72               // As/Bs row stride in shorts (144 B, 16B-aligned)
#define BLOCK  256
#define CSCALE 0.84932180f      // sqrt(0.5*log2(e)): exp(-0.5 d^2)=2^(-(d*C)^2)

#if __has_builtin(__builtin_amdgcn_exp2f)
  #define EXPN(t2) __builtin_amdgcn_exp2f(-(t2))
#else
  #define EXPN(t2) __expf(-(t2) * 0.69314718f)
#endif

typedef __attribute__((ext_vector_type(8))) short bf16x8;
typedef __attribute__((ext_vector_type(4))) float f32x4;
typedef __attribute__((ext_vector_type(2))) float f32x2;

// pack two f32 -> packed bf16 (lo = first arg)
__device__ __forceinline__ unsigned pack2bf(float a, float b) {
#if __has_builtin(__builtin_amdgcn_cvt_pk_bf16_f32)
    auto r = __builtin_amdgcn_cvt_pk_bf16_f32(a, b);   // v_cvt_pk_bf16_f32
    return __builtin_bit_cast(unsigned, r);
#else
    unsigned ua = __builtin_bit_cast(unsigned, a) + 0x8000u;  // round-half-up
    unsigned ub = __builtin_bit_cast(unsigned, b) + 0x8000u;
    return __builtin_amdgcn_perm(ub, ua, 0x07060302u);        // lo16 = bf16(a)
#endif
}

// kernel value pair: exp(-(p-b)^2) for 2 particles against one bin (packed math)
__device__ __forceinline__ unsigned kpair(f32x2 p, f32x2 b2) {
    const f32x2 d = p - b2;          // v_pk_add_f32 (neg)
    const f32x2 q = d * d;           // v_pk_mul_f32
    return pack2bf(EXPN(q[0]), EXPN(q[1]));  // neg folds into v_exp src mod
}

__global__ __launch_bounds__(BLOCK) void kde_gemm(
    const float* __restrict__ xs, const float* __restrict__ ys,
    const float* __restrict__ bins, float* __restrict__ accb,
    float* __restrict__ ws2)
{
    __shared__ short As[BM][LDK];     // 18432 B  kx tile [i-bin][k]
    __shared__ short Bs[BN][LDK];     // 18432 B  ky tile [j-bin][k]
    __shared__ float px[KCH];         // 3328 B
    __shared__ float py[KCH];         // 3328 B
    __shared__ float sred[4];

    const int tid   = threadIdx.x;
    const int tile  = blockIdx.x;            // 0..3 -> 2x2 tiles of 128
    const int chunk = blockIdx.y;            // 0..NCH-1
    const int b     = blockIdx.z;

    const int ilo = (tile & 1) * BM;
    const int jlo = (tile >> 1) * BN;
    const float s = CSCALE / (bins[1] - bins[0]);

    // ---- stage this chunk's particles (scaled) into LDS ----
    const float* xb = xs + b * N_;
    const float* yb = ys + b * N_;
    const int k0 = chunk * KCH;
    for (int t = tid; t < KCH; t += BLOCK) {
        const int k = k0 + t;
        const bool ok = (k < N_);
        px[t] = ok ? xb[k] * s : 3.0e30f;    // pad -> q = inf -> exp2(-inf)=0
        py[t] = ok ? yb[k] * s : 3.0e30f;
    }

    // staging role: thread covers bin=tid>>1, k-half kh
    const int  sbin = tid >> 1;
    const int  kh   = (tid & 1) * 32;
    const float bxs = bins[ilo + sbin] * s;
    const float bys = bins[jlo + sbin] * s;
    const f32x2 bx2 = {bxs, bxs};
    const f32x2 by2 = {bys, bys};

    // MFMA role: 4 waves in 2x2, each owns 64x64 of the 128x128 tile
    const int w    = tid >> 6;
    const int wi   = (w >> 1) * 64;
    const int wj   = (w & 1) * 64;
    const int lane = tid & 63;
    const int lm   = lane & 15;
    const int quad = lane >> 4;

    f32x4 zero = {0.f, 0.f, 0.f, 0.f};
    f32x4 acc[4][4];
    #pragma unroll
    for (int mt = 0; mt < 4; ++mt)
        #pragma unroll
        for (int nt = 0; nt < 4; ++nt) acc[mt][nt] = zero;

    for (int ks = 0; ks < KSTEPS; ++ks) {
        const int kb = ks * BK;
        __syncthreads();                      // covers px/py staging on ks==0
        // ---- 32 kx + 32 ky bf16 elements into LDS (pairwise packed) ----
        #pragma unroll
        for (int g = 0; g < 4; ++g) {
            const int k8 = kb + kh + g * 8;
            uint4 av, bv;
            av.x = kpair(*(const f32x2*)&px[k8 + 0], bx2);
            av.y = kpair(*(const f32x2*)&px[k8 + 2], bx2);
            av.z = kpair(*(const f32x2*)&px[k8 + 4], bx2);
            av.w = kpair(*(const f32x2*)&px[k8 + 6], bx2);
            bv.x = kpair(*(const f32x2*)&py[k8 + 0], by2);
            bv.y = kpair(*(const f32x2*)&py[k8 + 2], by2);
            bv.z = kpair(*(const f32x2*)&py[k8 + 4], by2);
            bv.w = kpair(*(const f32x2*)&py[k8 + 6], by2);
            *(uint4*)&As[sbin][kh + g * 8] = av;
            *(uint4*)&Bs[sbin][kh + g * 8] = bv;
        }
        __syncthreads();
        // ---- consume: 2 K-steps of 32, 16 MFMAs each ----
        #pragma unroll
        for (int kk = 0; kk < BK; kk += 32) {
            bf16x8 af[4], bfr[4];
            #pragma unroll
            for (int t4 = 0; t4 < 4; ++t4)
                af[t4] = *(const bf16x8*)&As[wi + t4 * 16 + lm][kk + quad * 8];
            #pragma unroll
            for (int t4 = 0; t4 < 4; ++t4)
                bfr[t4] = *(const bf16x8*)&Bs[wj + t4 * 16 + lm][kk + quad * 8];
            #pragma unroll
            for (int mt = 0; mt < 4; ++mt)
                #pragma unroll
                for (int nt = 0; nt < 4; ++nt)
                    acc[mt][nt] = __builtin_amdgcn_mfma_f32_16x16x32_bf16(
                        af[mt], bfr[nt], acc[mt][nt], 0, 0, 0);
        }
    }

    // ---- epilogue: atomic-accumulate into 1 MB buffer ----
    // C/D layout: col=lane&15, row=quad*4+reg. Wave's 64 lanes hit 64 distinct
    // addresses per instruction; cross-block conflicts spread over dispatch.
    float tsum = 0.f;
    {
        float* ab = accb + ((size_t)b << 16);
        #pragma unroll
        for (int mt = 0; mt < 4; ++mt) {
            const int row0 = ilo + wi + mt * 16 + quad * 4;
            #pragma unroll
            for (int nt = 0; nt < 4; ++nt) {
                const int col = jlo + wj + nt * 16 + lm;
                const f32x4 a = acc[mt][nt];
                #pragma unroll
                for (int e = 0; e < 4; ++e) {
                    unsafeAtomicAdd(&ab[(size_t)(row0 + e) * M_ + col], a[e]);
                    tsum += a[e];
                }
            }
        }
    }

    // ---- per-block sum -> ws2 (plain store; batch bb owns bids [bb*256,+256))
    #pragma unroll
    for (int off = 32; off; off >>= 1) tsum += __shfl_xor(tsum, off);
    if (lane == 0) sred[w] = tsum;
    __syncthreads();
    if (tid == 0) {
        const int bid = (blockIdx.z * gridDim.y + blockIdx.y) * gridDim.x + blockIdx.x;
        ws2[bid] = sred[0] + sred[1] + sred[2] + sred[3];
    }
}

__global__ __launch_bounds__(BLOCK) void kde_tail(
    const float* __restrict__ accb, const float* __restrict__ ws2,
    float* __restrict__ out)
{
    __shared__ float sred[4];
    __shared__ float snorm;
    const int tid = threadIdx.x;
    const int cellIdx = blockIdx.x * BLOCK + tid;   // float4 index, 16384/batch
    const int bb = cellIdx >> 14;                   // uniform per block

    // norm = sum of this batch's 256 block sums
    float t = ws2[(bb << 8) + tid];
    #pragma unroll
    for (int off = 32; off; off >>= 1) t += __shfl_xor(t, off);
    if ((tid & 63) == 0) sred[tid >> 6] = t;
    __syncthreads();
    if (tid == 0) snorm = sred[0] + sred[1] + sred[2] + sred[3];
    __syncthreads();

    const float sc = 1.0f / (snorm + 1e-10f);
    float4 v = ((const float4*)accb)[cellIdx];
    v.x *= sc; v.y *= sc; v.z *= sc; v.w *= sc;
    ((float4*)out)[cellIdx] = v;
}

extern "C" void kernel_launch(void* const* d_in, const int* in_sizes, int n_in,
                              void* d_out, int out_size, void* d_ws, size_t ws_size,
                              hipStream_t stream)
{
    const float* xs   = (const float*)d_in[0];
    const float* ys   = (const float*)d_in[1];
    const float* bins = (const float*)d_in[2];
    float* out  = (float*)d_out;
    float* accb = (float*)d_ws;                     // B*M*M f32 = 1 MB
    float* ws2  = accb + (size_t)B_ * M_ * M_;      // 1024 block sums

    // zero the accumulator (+ ws2 slack) every launch (ws is re-poisoned)
    hipMemsetAsync(d_ws, 0, ((size_t)B_ * M_ * M_ + 1024) * sizeof(float), stream);
    kde_gemm<<<dim3(4, NCH, B_), dim3(BLOCK), 0, stream>>>(xs, ys, bins, accb, ws2);
    kde_tail<<<dim3(B_ * M_ * M_ / (4 * BLOCK)), dim3(BLOCK), 0, stream>>>(accb, ws2, out);
}

// Round 7
// 105.343 us; speedup vs baseline: 2.0652x; 1.4466x over previous
//
#include <hip/hip_runtime.h>

// KDE joint histogram = dense split-K bf16 MFMA GEMM with SPARSE scatter
// staging. joint[b,i,j] = sum_k kx[b,k,i]*ky[b,k,j].
// Key fact: kx is nonzero (>= 2^-41) only within +-7.5 bins of the particle.
// Per K-step of 64 particles, 256 threads each own (particle, axis, 7-bin
// half-band): compute 7 bf16 kernel values via the Gaussian recurrence
//   E_{i+1} = E_i * G_i,  G_{i+1} = G_i * (1/e)   (uniform bins!)
// (2 exps per thread-step instead of 64) and scatter ds_write_b16 them into
// the zeroed LDS tiles; each thread re-zeroes its own previous 7 cells first
// (static column ownership -> race-free with a barrier between phases).
// MFMA consume + split-K partial stores as in the verified R3 structure.
// Tail kernel: reduce 32 partials/cell + norm + scale. 2 dispatches.

#define B_     4
#define N_     50000
#define M_     256
#define BK     64
#define NCH    32               // grid 4*32*4 = 512 = exactly 2 blocks/CU
#define KSTEPS 25               // 25*64 = 1600/chunk; 32*1600 = 51200 >= N
#define KCH    (KSTEPS * BK)
#define LDK    72               // tile row stride in shorts (144 B, 16B-aligned)
#define ROWS   129              // 128 + dump row for clipped writes
#define BLOCK  256
#define CS2    0.72134752f      // 0.5*log2(e):  exp(-0.5 d^2) = 2^(-CS2*d^2)
#define HINV   0.36787944f      // 2^(-2*CS2) = 1/e

#if __has_builtin(__builtin_amdgcn_exp2f)
  #define EXP2(t) __builtin_amdgcn_exp2f(t)
#else
  #define EXP2(t) exp2f(t)
#endif

typedef __attribute__((ext_vector_type(8))) short bf16x8;
typedef __attribute__((ext_vector_type(4))) float f32x4;

__device__ __forceinline__ short bf16ru(float f) {   // round-half-up to bf16
    return (short)((__builtin_bit_cast(unsigned, f) + 0x8000u) >> 16);
}

__global__ __launch_bounds__(BLOCK) void kde_gemm(
    const float* __restrict__ xs, const float* __restrict__ ys,
    const float* __restrict__ bins, float* __restrict__ partial,
    float* __restrict__ ws2, int wide)
{
    __shared__ short tiles[2][ROWS][LDK];   // 37152 B: [0]=As(kx), [1]=Bs(ky)
    __shared__ float pq[2][KCH];            // 12800 B: particle pos in BIN units
    __shared__ float sred[4];

    const int tid   = threadIdx.x;
    const int tile  = blockIdx.x;            // 0..3 -> 2x2 tiles of 128
    const int chunk = blockIdx.y;            // 0..NCH-1
    const int b     = blockIdx.z;

    const int ilo = (tile & 1) * 128;
    const int jlo = (tile >> 1) * 128;
    const float bin0  = bins[0];
    const float invbw = 1.0f / (bins[1] - bin0);

    // ---- bulk-zero tiles (incl. dump row) + stage particle positions ----
    {
        int4* za = (int4*)&tiles[0][0][0];   // 37152 B = 2322 int4, exact
        const int4 z4 = {0, 0, 0, 0};
        for (int t = tid; t < 2322; t += BLOCK) za[t] = z4;
        const float* xb = xs + b * N_;
        const float* yb = ys + b * N_;
        const int k0 = chunk * KCH;
        for (int t = tid; t < KCH; t += BLOCK) {
            const int k = k0 + t;
            const bool ok = (k < N_);
            pq[0][t] = ok ? (xb[k] - bin0) * invbw : 3.0e30f; // pad -> all-clip
            pq[1][t] = ok ? (yb[k] - bin0) * invbw : 3.0e30f;
        }
    }

    // scatter role: (particle column, axis, half-band)
    const int kcol = tid & 63;
    const int axis = (tid >> 6) & 1;         // 0 -> As, 1 -> Bs
    const int half = tid >> 7;               // 0: [i0-7,i0-1], 1: [i0,i0+6]
    const int rowlo = axis ? jlo : ilo;
    const unsigned axoff = (unsigned)axis * (ROWS * LDK) + (unsigned)kcol;
    const unsigned dump  = axoff + 128u * LDK;
    short* const tb = &tiles[0][0][0];
    unsigned sv[7];                          // previous step's cell offsets
    #pragma unroll
    for (int j = 0; j < 7; ++j) sv[j] = dump;

    // MFMA role: 4 waves in 2x2, each owns 64x64 of the 128x128 tile
    const int w    = tid >> 6;
    const int wi   = (w >> 1) * 64;
    const int wj   = (w & 1) * 64;
    const int lane = tid & 63;
    const int lm   = lane & 15;
    const int quad = lane >> 4;

    f32x4 zero = {0.f, 0.f, 0.f, 0.f};
    f32x4 acc[4][4];
    #pragma unroll
    for (int mt = 0; mt < 4; ++mt)
        #pragma unroll
        for (int nt = 0; nt < 4; ++nt) acc[mt][nt] = zero;

    __syncthreads();                         // staging + bulk zero complete

    for (int ks = 0; ks < KSTEPS; ++ks) {
        // ---- phase Z: self-clean previous writes (own column only) ----
        #pragma unroll
        for (int j = 0; j < 7; ++j) tb[sv[j]] = 0;
        __syncthreads();

        // ---- phase S: scatter 7-bin half-band via Gaussian recurrence ----
        {
            const float u    = pq[axis][ks * BK + kcol];   // bin units
            const float i0f  = rintf(u);
            const float strt = half ? i0f : (i0f - 7.0f);
            const float d0   = u - strt;                   // in [-0.5, 7.5]
            float E = EXP2(-CS2 * (d0 * d0));              // 2^(-CS2*d0^2)
            float G = EXP2(fmaf(d0 + d0, CS2, -CS2));      // 2^(CS2*(2d0-1))
            int   rr = (int)strt - rowlo;                  // local row
            #pragma unroll
            for (int j = 0; j < 7; ++j) {
                const unsigned off =
                    ((unsigned)rr < 128u) ? (axoff + (unsigned)rr * LDK) : dump;
                tb[off] = bf16ru(E);
                sv[j] = off;
                E *= G; G *= HINV; ++rr;
            }
        }
        __syncthreads();

        // ---- phase C: consume, 2 K-halves of 32, 16 MFMAs each ----
        #pragma unroll
        for (int kk = 0; kk < BK; kk += 32) {
            bf16x8 af[4], bfr[4];
            #pragma unroll
            for (int t4 = 0; t4 < 4; ++t4)
                af[t4] = *(const bf16x8*)&tiles[0][wi + t4 * 16 + lm][kk + quad * 8];
            #pragma unroll
            for (int t4 = 0; t4 < 4; ++t4)
                bfr[t4] = *(const bf16x8*)&tiles[1][wj + t4 * 16 + lm][kk + quad * 8];
            #pragma unroll
            for (int mt = 0; mt < 4; ++mt)
                #pragma unroll
                for (int nt = 0; nt < 4; ++nt)
                    acc[mt][nt] = __builtin_amdgcn_mfma_f32_16x16x32_bf16(
                        af[mt], bfr[nt], acc[mt][nt], 0, 0, 0);
        }
        __syncthreads();
    }

    // ---- epilogue: split-K partial store (C/D: col=lane&15, row=quad*4+e) ----
    float tsum = 0.f;
    {
        float* pb = partial + (((size_t)chunk * B_ + b) << 16);
        #pragma unroll
        for (int mt = 0; mt < 4; ++mt) {
            const int row0 = ilo + wi + mt * 16 + quad * 4;
            #pragma unroll
            for (int nt = 0; nt < 4; ++nt) {
                const int col = jlo + wj + nt * 16 + lm;
                const f32x4 a = acc[mt][nt];
                #pragma unroll
                for (int e = 0; e < 4; ++e) {
                    pb[(size_t)(row0 + e) * M_ + col] = a[e];
                    tsum += a[e];
                }
            }
        }
    }

    // ---- block sum -> ws2 ----
    #pragma unroll
    for (int off = 32; off; off >>= 1) tsum += __shfl_xor(tsum, off);
    if (lane == 0) sred[w] = tsum;
    __syncthreads();
    if (tid == 0) {
        const float bsum = sred[0] + sred[1] + sred[2] + sred[3];
        if (wide) {
            // bid in [b*128, (b+1)*128): plain store, no init needed
            const int bid = (b * NCH + chunk) * 4 + tile;
            ws2[bid] = bsum;
        } else {
            atomicAdd(&ws2[b], bsum);        // 4-float path (pre-zeroed)
        }
    }
}

__global__ __launch_bounds__(BLOCK) void kde_tail(
    const float* __restrict__ partial, const float* __restrict__ ws2,
    float* __restrict__ out, int wide)
{
    __shared__ float sred[4];
    __shared__ float snorm;
    const int tid = threadIdx.x;
    const int cellIdx = blockIdx.x * BLOCK + tid;   // float4 index, 16384/batch
    const int bb = cellIdx >> 14;                   // uniform per block
    const int cb = cellIdx & 16383;

    float nrm;
    if (wide) {
        float t = (tid < 128) ? ws2[(bb << 7) + tid] : 0.f;
        #pragma unroll
        for (int off = 32; off; off >>= 1) t += __shfl_xor(t, off);
        if ((tid & 63) == 0) sred[tid >> 6] = t;
        __syncthreads();
        if (tid == 0) snorm = sred[0] + sred[1] + sred[2] + sred[3];
        __syncthreads();
        nrm = snorm;
    } else {
        nrm = ws2[bb];
    }

    const float4* p4 = (const float4*)partial;
    float4 a = {0.f, 0.f, 0.f, 0.f};
    #pragma unroll 4
    for (int c = 0; c < NCH; ++c) {
        const float4 v = p4[(((size_t)c * B_ + bb) << 14) + cb];
        a.x += v.x; a.y += v.y; a.z += v.z; a.w += v.w;
    }
    const float sc = 1.0f / (nrm + 1e-10f);
    a.x *= sc; a.y *= sc; a.z *= sc; a.w *= sc;
    ((float4*)out)[cellIdx] = a;
}

extern "C" void kernel_launch(void* const* d_in, const int* in_sizes, int n_in,
                              void* d_out, int out_size, void* d_ws, size_t ws_size,
                              hipStream_t stream)
{
    const float* xs   = (const float*)d_in[0];
    const float* ys   = (const float*)d_in[1];
    const float* bins = (const float*)d_in[2];
    float* out     = (float*)d_out;
    float* partial = (float*)d_ws;                          // 32 MB
    const size_t PSZ = (size_t)NCH * B_ * M_ * M_ * sizeof(float);
    float* ws2 = (float*)((char*)d_ws + PSZ);

    // wide: 512 plain block-sum slots; narrow (ws proven >= PSZ+64 in R3):
    // 4-float atomic norm, needs a tiny memset.
    const int wide = (ws_size >= PSZ + 512 * sizeof(float)) ? 1 : 0;
    if (!wide) hipMemsetAsync(ws2, 0, 4 * sizeof(float), stream);

    kde_gemm<<<dim3(4, NCH, B_), dim3(BLOCK), 0, stream>>>(
        xs, ys, bins, partial, ws2, wide);
    kde_tail<<<dim3(B_ * M_ * M_ / (4 * BLOCK)), dim3(BLOCK), 0, stream>>>(
        partial, ws2, out, wide);
}

// Round 8
// 102.508 us; speedup vs baseline: 2.1223x; 1.0276x over previous
//
#include <hip/hip_runtime.h>

// KDE joint histogram = dense split-K bf16 MFMA GEMM with sparse scatter
// staging and PING-PONG K-tiles (1 barrier per K-step).
// joint[b,i,j] = sum_k kx[b,k,i]*ky[b,k,j]; kx nonzero only within ~±5.5 bins.
// Per K-step of 64 particles: 128 scatter threads (waves 0-1) each own one
// (particle, axis) column privately: clean their previous 12 cells, write 12
// new bf16 kernel values via the Gaussian recurrence E*=G, G*=1/e (2 exps),
// into buf[p^1] — while ALL 4 waves MFMA-consume buf[p]. Disjoint buffers ->
// single __syncthreads per step. Particle coords prefetched from global one
// iteration ahead (no LDS pq array). Split-K partials -> tail reduce kernel.

#define B_     4
#define N_     50000
#define M_     256
#define BK     64
#define NCH    32               // grid 4*32*4 = 512 = 2 blocks/CU
#define KSTEPS 25               // 25*64 = 1600/chunk; 32*1600 = 51200 >= N
#define KCH    (KSTEPS * BK)
#define LDK    72               // tile row stride in shorts (144 B, 16B-aligned)
#define ROWS   129              // 128 + dump row for clipped writes
#define BUFS   (2 * ROWS * LDK) // shorts per ping-pong buffer (both axes)
#define BLOCK  256
#define WINB   12               // bins per particle-axis window (±5.5 cutoff)
#define CS2    0.72134752f      // 0.5*log2(e): exp(-0.5 d^2) = 2^(-CS2*d^2)
#define HINV   0.36787944f      // 2^(-2*CS2) = 1/e

#if __has_builtin(__builtin_amdgcn_exp2f)
  #define EXP2(t) __builtin_amdgcn_exp2f(t)
#else
  #define EXP2(t) exp2f(t)
#endif

typedef __attribute__((ext_vector_type(8))) short bf16x8;
typedef __attribute__((ext_vector_type(4))) float f32x4;

__device__ __forceinline__ short bf16ru(float f) {   // round-half-up to bf16
    return (short)((__builtin_bit_cast(unsigned, f) + 0x8000u) >> 16);
}

__global__ __launch_bounds__(BLOCK) void kde_gemm(
    const float* __restrict__ xs, const float* __restrict__ ys,
    const float* __restrict__ bins, float* __restrict__ partial,
    float* __restrict__ ws2, int wide)
{
    __shared__ short tiles[2][2][ROWS][LDK];  // 74304 B: [buf][axis][row][k]
    __shared__ float sred[4];

    const int tid   = threadIdx.x;
    const int tile  = blockIdx.x;            // 0..3 -> 2x2 tiles of 128
    const int chunk = blockIdx.y;            // 0..NCH-1
    const int b     = blockIdx.z;

    const int ilo = (tile & 1) * 128;
    const int jlo = (tile >> 1) * 128;
    const float bin0  = bins[0];
    const float invbw = 1.0f / (bins[1] - bin0);

    // ---- bulk-zero both buffers (incl. dump rows) ----
    {
        int4* za = (int4*)&tiles[0][0][0][0];
        const int4 z4 = {0, 0, 0, 0};
        for (int t = tid; t < (int)(sizeof(tiles) / 16); t += BLOCK) za[t] = z4;
    }

    // ---- scatter role: thread-private (particle column, axis) ----
    const bool sc   = (tid < 128);
    const int  kcol = tid & 63;
    const int  axis = (tid >> 6) & 1;        // 0 -> As(kx), 1 -> Bs(ky)
    const int  rowlo = axis ? jlo : ilo;
    const int  base0 = axis * (ROWS * LDK) + kcol;   // buf-0 column base (shorts)
    short* const tb  = &tiles[0][0][0][0];
    const float* pb_ = (axis ? ys : xs) + b * N_;
    const int  k0   = chunk * KCH;
    int ps0 = 1 << 20, ps1 = 1 << 20;        // prev start-row per buffer (sentinel)

    // ---- MFMA role: 4 waves 2x2, each owns 64x64 of the 128x128 tile ----
    const int w    = tid >> 6;
    const int wi   = (w >> 1) * 64;
    const int wj   = (w & 1) * 64;
    const int lane = tid & 63;
    const int lm   = lane & 15;
    const int quad = lane >> 4;

    f32x4 zero = {0.f, 0.f, 0.f, 0.f};
    f32x4 acc[4][4];
    #pragma unroll
    for (int mt = 0; mt < 4; ++mt)
        #pragma unroll
        for (int nt = 0; nt < 4; ++nt) acc[mt][nt] = zero;

    // ---- preload windows 0 and 1 ----
    float v0 = 3.0e30f, vnext = 3.0e30f;     // pad -> rows clip to dump
    if (sc) {
        const int ka = k0 + kcol;
        if (ka < N_) v0 = pb_[ka];
        const int kb2 = k0 + BK + kcol;
        if (kb2 < N_) vnext = pb_[kb2];
    }

    __syncthreads();                         // bulk zero complete

    // ---- prologue: scatter window 0 -> buf 0 (pre-zeroed, no clean) ----
    if (sc) {
        const float u  = (v0 - bin0) * invbw;
        const float st = rintf(u) - 6.0f;    // window [i0-6, i0+5]
        const float d0 = u - st;             // in [5.5, 6.5]
        float E = EXP2(-CS2 * d0 * d0);
        float G = EXP2(fmaf(d0 + d0, CS2, -CS2));
        int rr = (int)st - rowlo;
        ps0 = rr;
        const int dmp = base0 + 128 * LDK;
        #pragma unroll
        for (int j = 0; j < WINB; ++j) {
            tb[((unsigned)rr < 128u) ? (base0 + rr * LDK) : dmp] = bf16ru(E);
            E *= G; G *= HINV; ++rr;
        }
    }
    __syncthreads();

    for (int ks = 0; ks < KSTEPS; ++ks) {
        const int q = ks & 1;
        // ---- prefetch window ks+2 (used next iteration) ----
        float vpre = 3.0e30f;
        if (sc && (ks + 2) < KSTEPS) {
            const int ka = k0 + (ks + 2) * BK + kcol;
            if (ka < N_) vpre = pb_[ka];
        }
        // ---- scatter window ks+1 into buf q^1 (clean own old cells first) ----
        if (sc && (ks + 1) < KSTEPS) {
            const int qn  = q ^ 1;
            const int bqn = qn * BUFS + base0;
            const int dmp = bqn + 128 * LDK;
            const int ps  = qn ? ps1 : ps0;
            if (ps < (1 << 19)) {
                #pragma unroll
                for (int j = 0; j < WINB; ++j) {
                    const int rr = ps + j;
                    tb[((unsigned)rr < 128u) ? (bqn + rr * LDK) : dmp] = 0;
                }
            }
            const float u  = (vnext - bin0) * invbw;
            const float st = rintf(u) - 6.0f;
            const float d0 = u - st;
            float E = EXP2(-CS2 * d0 * d0);
            float G = EXP2(fmaf(d0 + d0, CS2, -CS2));
            int rr = (int)st - rowlo;
            if (qn) ps1 = rr; else ps0 = rr;
            #pragma unroll
            for (int j = 0; j < WINB; ++j) {
                tb[((unsigned)rr < 128u) ? (bqn + rr * LDK) : dmp] = bf16ru(E);
                E *= G; G *= HINV; ++rr;
            }
        }
        vnext = vpre;

        // ---- consume buf q: 2 K-halves of 32, 16 MFMAs each ----
        #pragma unroll
        for (int kk = 0; kk < BK; kk += 32) {
            bf16x8 af[4], bfr[4];
            #pragma unroll
            for (int t4 = 0; t4 < 4; ++t4)
                af[t4] = *(const bf16x8*)&tiles[q][0][wi + t4 * 16 + lm][kk + quad * 8];
            #pragma unroll
            for (int t4 = 0; t4 < 4; ++t4)
                bfr[t4] = *(const bf16x8*)&tiles[q][1][wj + t4 * 16 + lm][kk + quad * 8];
            #pragma unroll
            for (int mt = 0; mt < 4; ++mt)
                #pragma unroll
                for (int nt = 0; nt < 4; ++nt)
                    acc[mt][nt] = __builtin_amdgcn_mfma_f32_16x16x32_bf16(
                        af[mt], bfr[nt], acc[mt][nt], 0, 0, 0);
        }
        __syncthreads();                     // the ONLY barrier per step
    }

    // ---- epilogue: split-K partial store (C/D: col=lane&15, row=quad*4+e) ----
    float tsum = 0.f;
    {
        float* pb = partial + (((size_t)chunk * B_ + b) << 16);
        #pragma unroll
        for (int mt = 0; mt < 4; ++mt) {
            const int row0 = ilo + wi + mt * 16 + quad * 4;
            #pragma unroll
            for (int nt = 0; nt < 4; ++nt) {
                const int col = jlo + wj + nt * 16 + lm;
                const f32x4 a = acc[mt][nt];
                #pragma unroll
                for (int e = 0; e < 4; ++e) {
                    pb[(size_t)(row0 + e) * M_ + col] = a[e];
                    tsum += a[e];
                }
            }
        }
    }

    // ---- block sum -> ws2 ----
    #pragma unroll
    for (int off = 32; off; off >>= 1) tsum += __shfl_xor(tsum, off);
    if (lane == 0) sred[w] = tsum;
    __syncthreads();
    if (tid == 0) {
        const float bsum = sred[0] + sred[1] + sred[2] + sred[3];
        if (wide) {
            const int bid = (b * NCH + chunk) * 4 + tile;  // in [b*128, +128)
            ws2[bid] = bsum;
        } else {
            atomicAdd(&ws2[b], bsum);
        }
    }
}

__global__ __launch_bounds__(BLOCK) void kde_tail(
    const float* __restrict__ partial, const float* __restrict__ ws2,
    float* __restrict__ out, int wide)
{
    __shared__ float sred[4];
    __shared__ float snorm;
    const int tid = threadIdx.x;
    const int cellIdx = blockIdx.x * BLOCK + tid;   // float4 index, 16384/batch
    const int bb = cellIdx >> 14;                   // uniform per block
    const int cb = cellIdx & 16383;

    float nrm;
    if (wide) {
        float t = (tid < 128) ? ws2[(bb << 7) + tid] : 0.f;
        #pragma unroll
        for (int off = 32; off; off >>= 1) t += __shfl_xor(t, off);
        if ((tid & 63) == 0) sred[tid >> 6] = t;
        __syncthreads();
        if (tid == 0) snorm = sred[0] + sred[1] + sred[2] + sred[3];
        __syncthreads();
        nrm = snorm;
    } else {
        nrm = ws2[bb];
    }

    const float4* p4 = (const float4*)partial;
    float4 a = {0.f, 0.f, 0.f, 0.f};
    #pragma unroll 4
    for (int c = 0; c < NCH; ++c) {
        const float4 v = p4[(((size_t)c * B_ + bb) << 14) + cb];
        a.x += v.x; a.y += v.y; a.z += v.z; a.w += v.w;
    }
    const float sc = 1.0f / (nrm + 1e-10f);
    a.x *= sc; a.y *= sc; a.z *= sc; a.w *= sc;
    ((float4*)out)[cellIdx] = a;
}

extern "C" void kernel_launch(void* const* d_in, const int* in_sizes, int n_in,
                              void* d_out, int out_size, void* d_ws, size_t ws_size,
                              hipStream_t stream)
{
    const float* xs   = (const float*)d_in[0];
    const float* ys   = (const float*)d_in[1];
    const float* bins = (const float*)d_in[2];
    float* out     = (float*)d_out;
    float* partial = (float*)d_ws;                          // 32 MB
    const size_t PSZ = (size_t)NCH * B_ * M_ * M_ * sizeof(float);
    float* ws2 = (float*)((char*)d_ws + PSZ);

    const int wide = (ws_size >= PSZ + 512 * sizeof(float)) ? 1 : 0;
    if (!wide) hipMemsetAsync(ws2, 0, 4 * sizeof(float), stream);

    kde_gemm<<<dim3(4, NCH, B_), dim3(BLOCK), 0, stream>>>(
        xs, ys, bins, partial, ws2, wide);
    kde_tail<<<dim3(B_ * M_ * M_ / (4 * BLOCK)), dim3(BLOCK), 0, stream>>>(
        partial, ws2, out, wide);
}

// Round 9
// 99.584 us; speedup vs baseline: 2.1846x; 1.0294x over previous
//
#include <hip/hip_runtime.h>

// KDE joint histogram = dense split-K bf16 MFMA GEMM, sparse scatter staging,
// ping-pong K-tiles (1 barrier/step), ASYMMETRIC wave tiles for load balance.
// joint[b,i,j] = sum_k kx[b,k,i]*ky[b,k,j]; kx nonzero within ~±4.5 bins.
// Waves 0-1: scatter duty (128 private (particle,axis) columns, 10-bin windows
//   via Gaussian recurrence E*=G, G*=1/e) + small consume tile (rows 0-47).
// Waves 2-3: big consume tile (rows 48-127). Same total MFMA/DS volume,
//   balanced per-wave issue. Split-K partials -> tail reduce+norm+scale.

#define B_     4
#define N_     50000
#define M_     256
#define BK     64
#define NCH    32               // grid 4*32*4 = 512 = 2 blocks/CU
#define KSTEPS 25               // 25*64 = 1600/chunk; 32*1600 = 51200 >= N
#define KCH    (KSTEPS * BK)
#define LDK    72               // tile row stride in shorts (144 B, 16B-aligned)
#define ROWS   129              // 128 + dump row for clipped writes
#define BUFS   (2 * ROWS * LDK) // shorts per ping-pong buffer (both axes)
#define BLOCK  256
#define WINB   10               // bins per particle-axis window (±4.5 cutoff)
#define CS2    0.72134752f      // 0.5*log2(e): exp(-0.5 d^2) = 2^(-CS2*d^2)
#define HINV   0.36787944f      // 2^(-2*CS2) = 1/e

#if __has_builtin(__builtin_amdgcn_exp2f)
  #define EXP2(t) __builtin_amdgcn_exp2f(t)
#else
  #define EXP2(t) exp2f(t)
#endif

typedef __attribute__((ext_vector_type(8))) short bf16x8;
typedef __attribute__((ext_vector_type(4))) float f32x4;

__device__ __forceinline__ short bf16ru(float f) {   // round-half-up to bf16
    return (short)((__builtin_bit_cast(unsigned, f) + 0x8000u) >> 16);
}

// One chunk's K-loop + epilogue for a wave with MT row-fragments starting at
// local row R0. SCAT waves additionally own one (particle,axis) scatter column.
// All instantiations execute identical barrier sequences.
template<int MT, int R0, bool SCAT>
__device__ __forceinline__ float chunk_loop(
    short* __restrict__ tb, const float* __restrict__ coord,
    int k0, int rowlo, int base0, float bin0, float invbw,
    int ilo, int jlo, int wj, int lm, int quad, int tid,
    float* __restrict__ pb)
{
    f32x4 acc[MT][4];
    #pragma unroll
    for (int mt = 0; mt < MT; ++mt)
        #pragma unroll
        for (int nt = 0; nt < 4; ++nt) acc[mt][nt] = f32x4{0.f, 0.f, 0.f, 0.f};

    int ps0 = 1 << 20, ps1 = 1 << 20;        // prev start-row per buffer
    const int dmp0 = base0 + 128 * LDK;      // buf-0 dump cell for this column

    float v0 = 3.0e30f, vnext = 3.0e30f;
    if (SCAT) {
        const int kcol = tid & 63;
        const int ka = k0 + kcol;       if (ka  < N_) v0    = coord[ka];
        const int kb2 = k0 + BK + kcol; if (kb2 < N_) vnext = coord[kb2];
    }
    __syncthreads();                         // bulk zero complete

    // ---- prologue: scatter window 0 -> buf 0 (pre-zeroed, no clean) ----
    if (SCAT) {
        const float u  = (v0 - bin0) * invbw;
        const float st = rintf(u) - 5.0f;    // window [i0-5, i0+4]
        const float d0 = u - st;             // in [4.5, 5.5]
        float E = EXP2(-CS2 * d0 * d0);
        float G = EXP2(fmaf(d0 + d0, CS2, -CS2));
        int rr = (int)st - rowlo;
        ps0 = rr;
        #pragma unroll
        for (int j = 0; j < WINB; ++j) {
            tb[((unsigned)rr < 128u) ? (base0 + rr * LDK) : dmp0] = bf16ru(E);
            E *= G; G *= HINV; ++rr;
        }
    }
    __syncthreads();

    for (int ks = 0; ks < KSTEPS; ++ks) {
        const int q = ks & 1;
        // ---- prefetch window ks+2 ----
        float vpre = 3.0e30f;
        if (SCAT && (ks + 2) < KSTEPS) {
            const int ka = k0 + (ks + 2) * BK + (tid & 63);
            if (ka < N_) vpre = coord[ka];
        }
        // ---- scatter window ks+1 into buf q^1 (clean own old cells) ----
        if (SCAT && (ks + 1) < KSTEPS) {
            const int qn  = q ^ 1;
            const int bqn = qn * BUFS + base0;
            const int dmp = bqn + 128 * LDK;
            const int ps  = qn ? ps1 : ps0;
            if (ps < (1 << 19)) {
                #pragma unroll
                for (int j = 0; j < WINB; ++j) {
                    const int rr = ps + j;
                    tb[((unsigned)rr < 128u) ? (bqn + rr * LDK) : dmp] = 0;
                }
            }
            const float u  = (vnext - bin0) * invbw;
            const float st = rintf(u) - 5.0f;
            const float d0 = u - st;
            float E = EXP2(-CS2 * d0 * d0);
            float G = EXP2(fmaf(d0 + d0, CS2, -CS2));
            int rr = (int)st - rowlo;
            if (qn) ps1 = rr; else ps0 = rr;
            #pragma unroll
            for (int j = 0; j < WINB; ++j) {
                tb[((unsigned)rr < 128u) ? (bqn + rr * LDK) : dmp] = bf16ru(E);
                E *= G; G *= HINV; ++rr;
            }
        }
        vnext = vpre;

        // ---- consume buf q: rows [R0, R0+16*MT), cols [wj, wj+64) ----
        const short* bufA = tb + q * BUFS;               // axis 0 tile
        const short* bufB = tb + q * BUFS + ROWS * LDK;  // axis 1 tile
        #pragma unroll
        for (int kk = 0; kk < BK; kk += 32) {
            bf16x8 af[MT], bfr[4];
            #pragma unroll
            for (int t4 = 0; t4 < MT; ++t4)
                af[t4] = *(const bf16x8*)&bufA[(R0 + t4 * 16 + lm) * LDK + kk + quad * 8];
            #pragma unroll
            for (int t4 = 0; t4 < 4; ++t4)
                bfr[t4] = *(const bf16x8*)&bufB[(wj + t4 * 16 + lm) * LDK + kk + quad * 8];
            #pragma unroll
            for (int mt = 0; mt < MT; ++mt)
                #pragma unroll
                for (int nt = 0; nt < 4; ++nt)
                    acc[mt][nt] = __builtin_amdgcn_mfma_f32_16x16x32_bf16(
                        af[mt], bfr[nt], acc[mt][nt], 0, 0, 0);
        }
        __syncthreads();                     // the only barrier per step
    }

    // ---- epilogue: split-K partial store (C/D: col=lane&15, row=quad*4+e) ----
    float tsum = 0.f;
    #pragma unroll
    for (int mt = 0; mt < MT; ++mt) {
        const int row0 = ilo + R0 + mt * 16 + quad * 4;
        #pragma unroll
        for (int nt = 0; nt < 4; ++nt) {
            const int col = jlo + wj + nt * 16 + lm;
            const f32x4 a = acc[mt][nt];
            #pragma unroll
            for (int e = 0; e < 4; ++e) {
                pb[(size_t)(row0 + e) * M_ + col] = a[e];
                tsum += a[e];
            }
        }
    }
    return tsum;
}

__global__ __launch_bounds__(BLOCK) void kde_gemm(
    const float* __restrict__ xs, const float* __restrict__ ys,
    const float* __restrict__ bins, float* __restrict__ partial,
    float* __restrict__ ws2, int wide)
{
    __shared__ short tiles[2][2][ROWS][LDK];  // 74304 B: [buf][axis][row][k]
    __shared__ float sred[4];

    const int tid   = threadIdx.x;
    const int tile  = blockIdx.x;            // 0..3 -> 2x2 tiles of 128
    const int chunk = blockIdx.y;            // 0..NCH-1
    const int b     = blockIdx.z;

    const int ilo = (tile & 1) * 128;
    const int jlo = (tile >> 1) * 128;
    const float bin0  = bins[0];
    const float invbw = 1.0f / (bins[1] - bin0);

    // ---- bulk-zero both buffers (incl. dump rows) ----
    {
        int4* za = (int4*)&tiles[0][0][0][0];
        const int4 z4 = {0, 0, 0, 0};
        for (int t = tid; t < (int)(sizeof(tiles) / 16); t += BLOCK) za[t] = z4;
    }

    // scatter column params (meaningful for tid < 128)
    const int  axis  = (tid >> 6) & 1;       // 0 -> As(kx), 1 -> Bs(ky)
    const int  rowlo = axis ? jlo : ilo;
    const int  base0 = axis * (ROWS * LDK) + (tid & 63);
    const float* coord = (axis ? ys : xs) + b * N_;
    const int  k0 = chunk * KCH;
    short* const tb = &tiles[0][0][0][0];

    // MFMA role
    const int w    = tid >> 6;
    const int wj   = (w & 1) * 64;
    const int lane = tid & 63;
    const int lm   = lane & 15;
    const int quad = lane >> 4;
    float* pb = partial + (((size_t)chunk * B_ + b) << 16);

    float tsum;
    if (w < 2)   // waves 0-1: scatter + rows [0,48)
        tsum = chunk_loop<3, 0, true >(tb, coord, k0, rowlo, base0, bin0, invbw,
                                       ilo, jlo, wj, lm, quad, tid, pb);
    else         // waves 2-3: rows [48,128)
        tsum = chunk_loop<5, 48, false>(tb, coord, k0, rowlo, base0, bin0, invbw,
                                       ilo, jlo, wj, lm, quad, tid, pb);

    // ---- block sum -> ws2 ----
    #pragma unroll
    for (int off = 32; off; off >>= 1) tsum += __shfl_xor(tsum, off);
    if (lane == 0) sred[w] = tsum;
    __syncthreads();
    if (tid == 0) {
        const float bsum = sred[0] + sred[1] + sred[2] + sred[3];
        if (wide) {
            const int bid = (b * NCH + chunk) * 4 + tile;  // in [b*128, +128)
            ws2[bid] = bsum;
        } else {
            atomicAdd(&ws2[b], bsum);
        }
    }
}

__global__ __launch_bounds__(BLOCK) void kde_tail(
    const float* __restrict__ partial, const float* __restrict__ ws2,
    float* __restrict__ out, int wide)
{
    __shared__ float sred[4];
    __shared__ float snorm;
    const int tid = threadIdx.x;
    const int cellIdx = blockIdx.x * BLOCK + tid;   // float4 index, 16384/batch
    const int bb = cellIdx >> 14;                   // uniform per block
    const int cb = cellIdx & 16383;

    float nrm;
    if (wide) {
        float t = (tid < 128) ? ws2[(bb << 7) + tid] : 0.f;
        #pragma unroll
        for (int off = 32; off; off >>= 1) t += __shfl_xor(t, off);
        if ((tid & 63) == 0) sred[tid >> 6] = t;
        __syncthreads();
        if (tid == 0) snorm = sred[0] + sred[1] + sred[2] + sred[3];
        __syncthreads();
        nrm = snorm;
    } else {
        nrm = ws2[bb];
    }

    const float4* p4 = (const float4*)partial;
    float4 a = {0.f, 0.f, 0.f, 0.f};
    #pragma unroll 4
    for (int c = 0; c < NCH; ++c) {
        const float4 v = p4[(((size_t)c * B_ + bb) << 14) + cb];
        a.x += v.x; a.y += v.y; a.z += v.z; a.w += v.w;
    }
    const float sc = 1.0f / (nrm + 1e-10f);
    a.x *= sc; a.y *= sc; a.z *= sc; a.w *= sc;
    ((float4*)out)[cellIdx] = a;
}

extern "C" void kernel_launch(void* const* d_in, const int* in_sizes, int n_in,
                              void* d_out, int out_size, void* d_ws, size_t ws_size,
                              hipStream_t stream)
{
    const float* xs   = (const float*)d_in[0];
    const float* ys   = (const float*)d_in[1];
    const float* bins = (const float*)d_in[2];
    float* out     = (float*)d_out;
    float* partial = (float*)d_ws;                          // 32 MB
    const size_t PSZ = (size_t)NCH * B_ * M_ * M_ * sizeof(float);
    float* ws2 = (float*)((char*)d_ws + PSZ);

    const int wide = (ws_size >= PSZ + 512 * sizeof(float)) ? 1 : 0;
    if (!wide) hipMemsetAsync(ws2, 0, 4 * sizeof(float), stream);

    kde_gemm<<<dim3(4, NCH, B_), dim3(BLOCK), 0, stream>>>(
        xs, ys, bins, partial, ws2, wide);
    kde_tail<<<dim3(B_ * M_ * M_ / (4 * BLOCK)), dim3(BLOCK), 0, stream>>>(
        partial, ws2, out, wide);
}

// Round 11
// 89.785 us; speedup vs baseline: 2.4230x; 1.1091x over previous
//
#include <hip/hip_runtime.h>

// KDE joint histogram = dense split-K INT8 MFMA GEMM, sparse scatter staging,
// ping-pong K-tiles (1 barrier/step), asymmetric wave tiles.
// joint[b,i,j] = sum_k kx[b,k,i]*ky[b,k,j]; quantize q = round(127*kernel)
// (i8 zeroes below 1/254 -> inherent ±3.33-bin support, window = 7 bins).
// The 127^2 scale cancels in normalization; i32 accumulation is exact.
// mfma_i32_16x16x64_i8: K=64 per instr, b128 frag = 16 i8 -> DS read bytes
// and MFMA count both HALVE vs bf16. Any consistent k-permutation in LDS is
// valid (MFMA pairs A/B k-slots identically). bf16 split-K partials -> tail.

#define B_     4
#define N_     50000
#define M_     256
#define BK     64
#define NCH    48               // grid 4*48*4 = 768 = 3 blocks/CU (LDS 41.3KB)
#define KSTEPS 17               // 17*64 = 1088/chunk; 48*1088 = 52224 >= N
#define KCH    (KSTEPS * BK)
#define LDKB   80               // tile row stride in BYTES (16B-aligned)
#define ROWS   129              // 128 + dump row for clipped writes
#define AXB    (ROWS * LDKB)    // bytes per axis tile (10320)
#define BUFB   (2 * AXB)        // bytes per ping-pong buffer (20640)
#define BLOCK  256
#define WINB   7                // bins per window (covers ±3.5)
#define CS2    0.72134752f      // 0.5*log2(e): exp(-0.5 d^2) = 2^(-CS2*d^2)
#define HINV   0.36787944f      // 2^(-2*CS2) = 1/e

#if __has_builtin(__builtin_amdgcn_exp2f)
  #define EXP2(t) __builtin_amdgcn_exp2f(t)
#else
  #define EXP2(t) exp2f(t)
#endif

typedef __attribute__((ext_vector_type(4))) int i32x4;

__device__ __forceinline__ unsigned short bf16ru(float f) {  // round-half-up
    return (unsigned short)((__builtin_bit_cast(unsigned, f) + 0x8000u) >> 16);
}
__device__ __forceinline__ float bf2f(unsigned short u) {
    return __builtin_bit_cast(float, ((unsigned)u) << 16);
}

// One chunk's K-loop + epilogue for a wave with MT row-frags at local row R0.
// SCAT waves additionally own one (particle,axis) scatter column (byte colbase
// within each row). All instantiations execute identical barrier sequences.
template<int MT, int R0, bool SCAT>
__device__ __forceinline__ float chunk_loop(
    char* __restrict__ tb, const float* __restrict__ coord,
    int k0, int rowlo, int colbase, float bin0, float invbw,
    int ilo, int jlo, int wj, int lm, int quad, int tid,
    unsigned short* __restrict__ pb)
{
    i32x4 acc[MT][4];
    #pragma unroll
    for (int mt = 0; mt < MT; ++mt)
        #pragma unroll
        for (int nt = 0; nt < 4; ++nt) acc[mt][nt] = i32x4{0, 0, 0, 0};

    int ps0 = 1 << 20, ps1 = 1 << 20;        // prev start-row per buffer

    float v0 = 3.0e30f, vnext = 3.0e30f;     // pad -> rows clip to dump
    if (SCAT) {
        const int kcol = tid & 63;
        const int ka = k0 + kcol;       if (ka  < N_) v0    = coord[ka];
        const int kb2 = k0 + BK + kcol; if (kb2 < N_) vnext = coord[kb2];
    }
    __syncthreads();                         // bulk zero complete

    // ---- prologue: scatter window 0 -> buf 0 (pre-zeroed, no clean) ----
    if (SCAT) {
        const float u  = (v0 - bin0) * invbw;
        const float st = rintf(u) - 3.0f;    // window covers d in [-3.5, 3.5]
        const float d0 = u - st;             // in [2.5, 3.5]
        float E = 127.0f * EXP2(-CS2 * d0 * d0);
        float G = EXP2(fmaf(d0 + d0, CS2, -CS2));
        int rr = (int)st - rowlo;
        ps0 = rr;
        const int dmp = colbase + 128 * LDKB;
        #pragma unroll
        for (int j = 0; j < WINB; ++j) {
            tb[((unsigned)rr < 128u) ? (colbase + rr * LDKB) : dmp] =
                (char)(int)(E + 0.5f);
            E *= G; G *= HINV; ++rr;
        }
    }
    __syncthreads();

    for (int ks = 0; ks < KSTEPS; ++ks) {
        const int q = ks & 1;
        // ---- prefetch window ks+2 ----
        float vpre = 3.0e30f;
        if (SCAT && (ks + 2) < KSTEPS) {
            const int ka = k0 + (ks + 2) * BK + (tid & 63);
            if (ka < N_) vpre = coord[ka];
        }
        // ---- scatter window ks+1 into buf q^1 (clean own old cells) ----
        if (SCAT && (ks + 1) < KSTEPS) {
            const int qn  = q ^ 1;
            const int bqn = qn * BUFB + colbase;
            const int dmp = bqn + 128 * LDKB;
            const int ps  = qn ? ps1 : ps0;
            if (ps < (1 << 19)) {
                #pragma unroll
                for (int j = 0; j < WINB; ++j) {
                    const int rr = ps + j;
                    tb[((unsigned)rr < 128u) ? (bqn + rr * LDKB) : dmp] = 0;
                }
            }
            const float u  = (vnext - bin0) * invbw;
            const float st = rintf(u) - 3.0f;
            const float d0 = u - st;
            float E = 127.0f * EXP2(-CS2 * d0 * d0);
            float G = EXP2(fmaf(d0 + d0, CS2, -CS2));
            int rr = (int)st - rowlo;
            if (qn) ps1 = rr; else ps0 = rr;
            #pragma unroll
            for (int j = 0; j < WINB; ++j) {
                tb[((unsigned)rr < 128u) ? (bqn + rr * LDKB) : dmp] =
                    (char)(int)(E + 0.5f);
                E *= G; G *= HINV; ++rr;
            }
        }
        vnext = vpre;

        // ---- consume buf q: K=64 in ONE mfma per frag-pair ----
        const char* bufA = tb + q * BUFB;          // axis 0 (kx)
        const char* bufB = tb + q * BUFB + AXB;    // axis 1 (ky)
        i32x4 af[MT], bfr[4];
        #pragma unroll
        for (int t4 = 0; t4 < MT; ++t4)
            af[t4] = *(const i32x4*)(bufA + (R0 + t4 * 16 + lm) * LDKB + quad * 16);
        #pragma unroll
        for (int t4 = 0; t4 < 4; ++t4)
            bfr[t4] = *(const i32x4*)(bufB + (wj + t4 * 16 + lm) * LDKB + quad * 16);
        #pragma unroll
        for (int mt = 0; mt < MT; ++mt)
            #pragma unroll
            for (int nt = 0; nt < 4; ++nt)
                acc[mt][nt] = __builtin_amdgcn_mfma_i32_16x16x64_i8(
                    af[mt], bfr[nt], acc[mt][nt], 0, 0, 0);
        __syncthreads();                     // the only barrier per step
    }

    // ---- epilogue: bf16 split-K partial (C/D: col=lane&15, row=quad*4+e) ----
    float tsum = 0.f;
    #pragma unroll
    for (int mt = 0; mt < MT; ++mt) {
        const int row0 = ilo + R0 + mt * 16 + quad * 4;
        #pragma unroll
        for (int nt = 0; nt < 4; ++nt) {
            const int col = jlo + wj + nt * 16 + lm;
            const i32x4 a = acc[mt][nt];
            #pragma unroll
            for (int e = 0; e < 4; ++e) {
                const float v = (float)a[e];
                pb[(size_t)(row0 + e) * M_ + col] = bf16ru(v);
                tsum += v;
            }
        }
    }
    return tsum;
}

__global__ __launch_bounds__(BLOCK) void kde_gemm(
    const float* __restrict__ xs, const float* __restrict__ ys,
    const float* __restrict__ bins, unsigned short* __restrict__ partial,
    float* __restrict__ ws2, int wide)
{
    __shared__ __align__(16) char tiles[2][2][ROWS][LDKB];  // 41280 B
    __shared__ float sred[4];

    const int tid   = threadIdx.x;
    const int tile  = blockIdx.x;            // 0..3 -> 2x2 tiles of 128
    const int chunk = blockIdx.y;            // 0..NCH-1
    const int b     = blockIdx.z;

    const int ilo = (tile & 1) * 128;
    const int jlo = (tile >> 1) * 128;
    const float bin0  = bins[0];
    const float invbw = 1.0f / (bins[1] - bin0);

    // ---- bulk-zero both buffers (incl. dump rows) ----
    {
        int4* za = (int4*)&tiles[0][0][0][0];
        const int4 z4 = {0, 0, 0, 0};
        for (int t = tid; t < (int)(sizeof(tiles) / 16); t += BLOCK) za[t] = z4;
    }

    // scatter column params (meaningful for tid < 128)
    const int  axis    = (tid >> 6) & 1;     // 0 -> kx tile, 1 -> ky tile
    const int  rowlo   = axis ? jlo : ilo;
    const int  colbase = axis * AXB + (tid & 63);
    const float* coord = (axis ? ys : xs) + b * N_;
    const int  k0 = chunk * KCH;
    char* const tb = &tiles[0][0][0][0];

    // MFMA role
    const int w    = tid >> 6;
    const int wj   = (w & 1) * 64;
    const int lane = tid & 63;
    const int lm   = lane & 15;
    const int quad = lane >> 4;
    unsigned short* pb = partial + (((size_t)chunk * B_ + b) << 16);

    float tsum;
    if (w < 2)   // waves 0-1: scatter + rows [0,48)
        tsum = chunk_loop<3, 0, true >(tb, coord, k0, rowlo, colbase, bin0, invbw,
                                       ilo, jlo, wj, lm, quad, tid, pb);
    else         // waves 2-3: rows [48,128)
        tsum = chunk_loop<5, 48, false>(tb, coord, k0, rowlo, colbase, bin0, invbw,
                                       ilo, jlo, wj, lm, quad, tid, pb);

    // ---- block sum -> ws2 ----
    #pragma unroll
    for (int off = 32; off; off >>= 1) tsum += __shfl_xor(tsum, off);
    if (lane == 0) sred[w] = tsum;
    __syncthreads();
    if (tid == 0) {
        const float bsum = sred[0] + sred[1] + sred[2] + sred[3];
        if (wide) {
            const int bid = (b * NCH + chunk) * 4 + tile;  // in [b*192, +192)
            ws2[bid] = bsum;
        } else {
            atomicAdd(&ws2[b], bsum);
        }
    }
}

__global__ __launch_bounds__(BLOCK) void kde_tail(
    const unsigned short* __restrict__ partial, const float* __restrict__ ws2,
    float* __restrict__ out, int wide)
{
    __shared__ float sred[4];
    __shared__ float snorm;
    const int tid = threadIdx.x;
    const int cellIdx = blockIdx.x * BLOCK + tid;   // float4 index, 16384/batch
    const int bb = cellIdx >> 14;                   // uniform per block
    const int cb = cellIdx & 16383;

    float nrm;
    if (wide) {
        float t = (tid < 4 * NCH) ? ws2[bb * 4 * NCH + tid] : 0.f;
        #pragma unroll
        for (int off = 32; off; off >>= 1) t += __shfl_xor(t, off);
        if ((tid & 63) == 0) sred[tid >> 6] = t;
        __syncthreads();
        if (tid == 0) snorm = sred[0] + sred[1] + sred[2] + sred[3];
        __syncthreads();
        nrm = snorm;
    } else {
        nrm = ws2[bb];
    }

    float4 a = {0.f, 0.f, 0.f, 0.f};
    #pragma unroll 4
    for (int c = 0; c < NCH; ++c) {
        const ushort4 v = *(const ushort4*)(partial +
            (((size_t)c * B_ + bb) << 16) + (size_t)cb * 4);
        a.x += bf2f(v.x); a.y += bf2f(v.y); a.z += bf2f(v.z); a.w += bf2f(v.w);
    }
    // i8 scale (127^2) cancels: both partials and nrm carry it.
    const float sc = 1.0f / (nrm + 1e-10f);
    a.x *= sc; a.y *= sc; a.z *= sc; a.w *= sc;
    ((float4*)out)[cellIdx] = a;
}

extern "C" void kernel_launch(void* const* d_in, const int* in_sizes, int n_in,
                              void* d_out, int out_size, void* d_ws, size_t ws_size,
                              hipStream_t stream)
{
    const float* xs   = (const float*)d_in[0];
    const float* ys   = (const float*)d_in[1];
    const float* bins = (const float*)d_in[2];
    float* out = (float*)d_out;
    unsigned short* partial = (unsigned short*)d_ws;        // 24 MB bf16
    const size_t PSZ = (size_t)NCH * B_ * M_ * M_ * sizeof(unsigned short);
    float* ws2 = (float*)((char*)d_ws + PSZ);

    const int wide = (ws_size >= PSZ + 4096) ? 1 : 0;
    if (!wide) hipMemsetAsync(ws2, 0, 4 * sizeof(float), stream);

    kde_gemm<<<dim3(4, NCH, B_), dim3(BLOCK), 0, stream>>>(
        xs, ys, bins, partial, ws2, wide);
    kde_tail<<<dim3(B_ * M_ * M_ / (4 * BLOCK)), dim3(BLOCK), 0, stream>>>(
        partial, ws2, out, wide);
}